// Round 13
// baseline (234.889 us; speedup 1.0000x reference)
//
#include <hip/hip_runtime.h>
#include <hip/hip_bf16.h>
#include <math.h>

// GAT predictor: B=64, N=512, ATOM=34, GAT=128, HID=256, 3 layers + out.
// Round-20: (a) wt_prep(Wc) folded into the gemm384 dispatch (blocks >=1024
// of an 1152 grid; WcT parked in the DEAD layer-1 wht slot — nothing touches
// slot 1 after the merged fused_attn, and only the final GEMM reads it) —
// one dispatch + gap removed. (b) mfma_gemm gets the round-17-proven
// even/odd named-register B prefetch (gemm B loads were unbuffered between
// barriers). (c) fused_attn's src/mask loads hoisted to entry (independent
// of the dstS barrier; their L2 latency was on the phase-1 critical path).
// All bit-identical -> absmax 0.00390625. Tripwire: fused WRITE_SIZE 49152.
// ws: wht[3] 48MB (slot1 hosts WcT after merged attn) | multi 50MB
// d_out: mask 2.1MB | src[4]/dst[4] 1MB | WoT 0.4MB  (until final GEMM)

#define ALPHA 0.2f
#define LOG2E 1.44269504088896f

#if __has_builtin(__builtin_amdgcn_exp2f)
#define EXP2F(x) __builtin_amdgcn_exp2f(x)
#else
extern "C" __device__ float __ocml_exp2_f32(float);
#define EXP2F(x) __ocml_exp2_f32(x)
#endif

typedef __attribute__((ext_vector_type(8))) short s16x8;   // 8 bf16 (4 VGPRs)
typedef __attribute__((ext_vector_type(4))) float f32x4;

#define MF(a, b, c) c = __builtin_amdgcn_mfma_f32_16x16x32_bf16(a, b, c, 0, 0, 0)

__device__ __forceinline__ ushort bf16_rne(float f) {
  union { float f; unsigned u; } v; v.f = f;
  unsigned r = v.u + 0x7FFFu + ((v.u >> 16) & 1u);
  return (ushort)(r >> 16);
}
__device__ __forceinline__ float bf16_tof(ushort h) {
  union { unsigned u; float f; } v; v.u = ((unsigned)h) << 16;
  return v.f;
}
__device__ __forceinline__ void split_store4(
    ushort* __restrict__ ph, ushort* __restrict__ pl,
    float v0, float v1, float v2, float v3) {
  ushort h0 = bf16_rne(v0), h1 = bf16_rne(v1), h2 = bf16_rne(v2), h3 = bf16_rne(v3);
  *(ushort4*)ph = make_ushort4(h0, h1, h2, h3);
  *(ushort4*)pl = make_ushort4(bf16_rne(v0 - bf16_tof(h0)), bf16_rne(v1 - bf16_tof(h1)),
                               bf16_rne(v2 - bf16_tof(h2)), bf16_rne(v3 - bf16_tof(h3)));
}

// wht fragment-order offset (K=512): batch*65536 + (col/16)*8192 + (j/32)*512
//   + (col%16)*8 + ((j>>3)&3)*128 + (j&7)   [j = node index = GEMM k]
__device__ __forceinline__ long wht_off(long batch, int c, int j) {
  return batch * 65536 + (long)(c >> 4) * 8192 + (j >> 5) * 512 +
         ((c & 15) << 3) + (((j >> 3) & 3) << 7) + (j & 7);
}

// generic fragment-order offset for a [Kd x Nd] weight (col c, k-index j)
__device__ __forceinline__ long w_frag_off(int c, int j, int Kd) {
  return (long)(c >> 4) * (Kd * 16) + (j >> 5) * 512 +
         ((c & 15) << 3) + (((j >> 3) & 3) << 7) + (j & 7);
}

#define WHT_SLOT 8388608L   // ushorts per layer slot (whtH 4M + whtL 4M)

// ---- K0 (front union, INTERLEAVED): per 83-block group: 48 wh | 32 mask |
// 3 wt(W_out). Resident windows carry the global mix -> mask's HBM stream
// overlaps wh's compute. ----
__global__ __launch_bounds__(256) void front_union(
    const float* __restrict__ A, const float* __restrict__ Wst,
    const float* __restrict__ ast,
    ushort* __restrict__ whtBase, float* __restrict__ srcB, float* __restrict__ dstB,
    const int* __restrict__ adj, unsigned* __restrict__ mask,
    const float* __restrict__ W_out, ushort* __restrict__ WoT_H, ushort* __restrict__ WoT_L)
{
  __shared__ float AsT[34][36];
  __shared__ float Ws[34][128];
  const int t = threadIdx.x;
  const int g = blockIdx.x / 83, r83 = blockIdx.x - g * 83;

  if (r83 >= 48) {
    if (r83 < 80) {
      // ---- maskprep: pack adj>0 into bitmask [32768][16] uint ----
      const int mb = g * 32 + (r83 - 48);           // [0,2048)
      const int gid = mb * 256 + t;
      const int4* __restrict__ p = (const int4*)(adj + (long)gid * 32);
      unsigned m = 0;
#pragma unroll
      for (int k = 0; k < 8; k++) {
        const int4 v = p[k];
        m |= (v.x > 0 ? 1u : 0u) << (4 * k);
        m |= (v.y > 0 ? 1u : 0u) << (4 * k + 1);
        m |= (v.z > 0 ? 1u : 0u) << (4 * k + 2);
        m |= (v.w > 0 ? 1u : 0u) << (4 * k + 3);
      }
      mask[gid] = m;
    } else {
      // ---- wt_prep(W_out): [384,128] fp32 -> fragment-order WoT ----
      const int wb = g * 3 + (r83 - 80);            // [0,192)
      const int idx = wb * 256 + t;                 // 49152 exact
      const int k = idx / 128, n = idx % 128;
      const float v = W_out[idx];
      const ushort h = bf16_rne(v);
      const long o = w_frag_off(n, k, 384);
      WoT_H[o] = h;
      WoT_L[o] = bf16_rne(v - bf16_tof(h));
    }
    return;
  }

  // ---- wh_small: Wh_l = compound @ W_l -> whT_l (fragment order) + src/dst
  const int bid = g * 48 + r83;                     // [0,3072)
  const int l = bid >> 10;
  const float* __restrict__ W = Wst + (long)l * 34 * 128;
  const float* __restrict__ avec = ast + (long)l * 256;
  ushort* __restrict__ whtH = whtBase + (long)l * WHT_SLOT;
  ushort* __restrict__ whtL = whtH + 4194304;
  float* __restrict__ src = srcB + (long)l * 32768;
  float* __restrict__ dst = dstB + (long)l * 32768;
  const long row0 = (long)(bid & 1023) * 32;
  const int cg = t & 31, rg = t >> 5;
  {
    const int r = t >> 3, l8 = t & 7;
#pragma unroll
    for (int q = 0; q < 5; q++) {
      int k = l8 + q * 8;
      if (k < 34) AsT[k][r] = A[(row0 + r) * 34 + k];
    }
  }
  {
    int idx = t;
#pragma unroll
    for (int i = 0; i < 17; i++, idx += 256)
      Ws[idx >> 7][idx & 127] = W[idx];
  }
  __syncthreads();

  float acc[4][4];
#pragma unroll
  for (int r = 0; r < 4; r++)
#pragma unroll
    for (int c = 0; c < 4; c++) acc[r][c] = 0.f;
#pragma unroll 2
  for (int k = 0; k < 34; k++) {
    const float4 wv = *(const float4*)&Ws[k][cg * 4];
    const float4 av = *(const float4*)&AsT[k][rg * 4];
#define GFMA(r, a) \
    acc[r][0] += (a) * wv.x; acc[r][1] += (a) * wv.y; \
    acc[r][2] += (a) * wv.z; acc[r][3] += (a) * wv.w;
    GFMA(0, av.x) GFMA(1, av.y) GFMA(2, av.z) GFMA(3, av.w)
#undef GFMA
  }

  {
    const long batch = row0 >> 9;
    const int j = (int)(row0 & 511) + rg * 4;       // j%4 == 0 -> contiguous 4
#pragma unroll
    for (int cc = 0; cc < 4; cc++) {
      const long o = wht_off(batch, cg * 4 + cc, j);
      split_store4(&whtH[o], &whtL[o], acc[0][cc], acc[1][cc], acc[2][cc], acc[3][cc]);
    }
  }

  const float4 a1 = *(const float4*)&avec[cg * 4];
  const float4 a2 = *(const float4*)&avec[128 + cg * 4];
#pragma unroll
  for (int r = 0; r < 4; r++) {
    float s = acc[r][0]*a1.x + acc[r][1]*a1.y + acc[r][2]*a1.z + acc[r][3]*a1.w;
    float d = acc[r][0]*a2.x + acc[r][1]*a2.y + acc[r][2]*a2.z + acc[r][3]*a2.w;
#pragma unroll
    for (int w = 1; w < 32; w <<= 1) {
      s += __shfl_xor(s, w, 64);
      d += __shfl_xor(d, w, 64);
    }
    if (cg == 0) {
      src[row0 + rg * 4 + r] = s * LOG2E;   // log2-domain at producer
      dst[row0 + rg * 4 + r] = d * LOG2E;
    }
  }
}

// ---- K2 (fused, multi-layer): single-pass masked softmax -> LDS As
// (unnormalized bf16 p), then out = elu((P @ WhT^T) * 1/rowsum).
// blockIdx.z = layer. B prefetch: depth-4 named-register ping-pong;
// src/mask loads hoisted to entry. ----

#define LD_SET(S, KB) \
  S##0H = *(const s16x8*)&bH[(KB) * 512]; \
  S##0L = *(const s16x8*)&bL[(KB) * 512]; \
  S##1H = *(const s16x8*)&bH[8192 + (KB) * 512]; \
  S##1L = *(const s16x8*)&bL[8192 + (KB) * 512];

#define STEP(S, KB) { \
  const int k0_ = ((KB) * 32 + q * 8) ^ ((((KB) >> 1) & 7) << 3); \
  const s16x8 a0_ = *(const s16x8*)&As[m16][k0_]; \
  const s16x8 a1_ = *(const s16x8*)&As[16 + m16][k0_]; \
  MF(a0_, S##0H, acc00); MF(a0_, S##1H, acc01); \
  MF(a1_, S##0H, acc10); MF(a1_, S##1H, acc11); \
  MF(a0_, S##0L, acc00); MF(a0_, S##1L, acc01); \
  MF(a1_, S##0L, acc10); MF(a1_, S##1L, acc11); \
  if ((KB) + 4 < 16) { LD_SET(S, (KB) + 4) } }

__global__ __launch_bounds__(256, 4) void fused_attn(
    const unsigned* __restrict__ mask,
    const float* __restrict__ srcB, const float* __restrict__ dstB,
    const ushort* __restrict__ whtBase,
    float* __restrict__ out, const int ostride)
{
  __shared__ ushort As[32][520];
  __shared__ float dstS[544];          // phys = j + (j>>6)*4
  __shared__ float invS[32];
  __shared__ float wredM[4];
  const int t = threadIdx.x;
  const int l = blockIdx.z;
  const float* __restrict__ src = srcB + (long)l * 32768;
  const float* __restrict__ dstv = dstB + (long)l * 32768;
  const ushort* __restrict__ whtH = whtBase + (long)l * WHT_SLOT;
  const ushort* __restrict__ whtL = whtH + 4194304;
  const int ocoff = l * 128;
  // XCD swizzle: per layer 1024 blocks = 8 XCDs x 128; each XCD gets 8 whole
  // batches so a batch's 512KB wht slice is HBM-fetched once, reused via L2.
  const int flat = blockIdx.y * 16 + blockIdx.x;
  const int swz = (flat & 7) * 128 + (flat >> 3);
  const long base = (long)(swz >> 4) * 512;   // batch * 512
  const int i0 = (swz & 15) * 32;             // row tile within batch

  // MFMA geometry + entry prefetch of k-blocks 0..3 + phase-1 global inputs
  // (all independent of the dstS barrier; latency hides under staging).
  const int wv = t >> 6, lane = t & 63;
  const int m16 = lane & 15, q = lane >> 4;
  const int n0 = wv * 32;
  const ushort* __restrict__ bH = whtH + base * 128 + wv * 16384 + lane * 8;
  const ushort* __restrict__ bL = whtL + base * 128 + wv * 16384 + lane * 8;
  s16x8 sA0H, sA0L, sA1H, sA1L, sB0H, sB0L, sB1H, sB1L;
  s16x8 sC0H, sC0L, sC1H, sC1L, sD0H, sD0L, sD1H, sD1L;
  LD_SET(sA, 0)
  LD_SET(sB, 1)
  LD_SET(sC, 2)
  LD_SET(sD, 3)
  const int r1 = t >> 3, l8 = t & 7;
  const long irow = base + i0 + r1;
  const float si = src[irow];
  const uint2 mw2 = *(const uint2*)(mask + irow * 16 + 2 * l8);

  // stage dstS (already log2 domain, padded layout) + block-wide max md
  {
    const float d0 = dstv[base + t];
    const float d1 = dstv[base + t + 256];
    dstS[t + (t >> 6) * 4] = d0;
    const int t2 = t + 256;
    dstS[t2 + (t2 >> 6) * 4] = d1;
    float mx = fmaxf(d0, d1);
#pragma unroll
    for (int w = 1; w < 64; w <<= 1) mx = fmaxf(mx, __shfl_xor(mx, w, 64));
    if ((t & 63) == 0) wredM[t >> 6] = mx;
  }
  __syncthreads();
  const float md = fmaxf(fmaxf(wredM[0], wredM[1]), fmaxf(wredM[2], wredM[3]));

  // ---- phase 1: single-pass masked softmax -> As bf16, invS = 1/rowsum.
  // 8 threads per row, thread l8 owns contiguous j in [l8*64, l8*64+64).
  {
    const float em = si + md;
    const float m = fmaxf(em, ALPHA * em);   // >= masked max of leaky(si+dv)
    const float* __restrict__ dp = &dstS[l8 * 68];
    const int jb = l8 * 64;
    const int xs = l8 << 3;                  // As column XOR swizzle
    float sum = 0.f;
#pragma unroll
    for (int g = 0; g < 16; g++) {
      const float4 dv = *(const float4*)&dp[g * 4];
      const unsigned w = ((g & 8) ? mw2.y : mw2.x) >> ((g & 7) * 4);
      float e0 = si + dv.x, e1 = si + dv.y, e2 = si + dv.z, e3 = si + dv.w;
      e0 = fmaxf(e0, ALPHA * e0) - m; e1 = fmaxf(e1, ALPHA * e1) - m;
      e2 = fmaxf(e2, ALPHA * e2) - m; e3 = fmaxf(e3, ALPHA * e3) - m;
      float p0 = EXP2F(e0), p1 = EXP2F(e1), p2 = EXP2F(e2), p3 = EXP2F(e3);
      p0 = (w & 1u) ? p0 : 0.f;
      p1 = (w & 2u) ? p1 : 0.f;
      p2 = (w & 4u) ? p2 : 0.f;
      p3 = (w & 8u) ? p3 : 0.f;
      sum += (p0 + p1) + (p2 + p3);
      union { __hip_bfloat162 b; unsigned u; } u01, u23;
      u01.b = __float22bfloat162_rn(make_float2(p0, p1));
      u23.b = __float22bfloat162_rn(make_float2(p2, p3));
      *(uint2*)&As[r1][(jb + g * 4) ^ xs] = make_uint2(u01.u, u23.u);
    }
#pragma unroll
    for (int w = 1; w < 8; w <<= 1) sum += __shfl_xor(sum, w, 64);
    if (l8 == 0) invS[r1] = 1.f / sum;
  }
  __syncthreads();

  // ---- phase 2: MFMA aggregation, depth-4 named-register ping-pong.
  // As reads apply the same column XOR: ((kb>>1)&7)<<3, compile-time. ----
  f32x4 acc00 = {0.f,0.f,0.f,0.f}, acc01 = {0.f,0.f,0.f,0.f};
  f32x4 acc10 = {0.f,0.f,0.f,0.f}, acc11 = {0.f,0.f,0.f,0.f};
#pragma unroll
  for (int kp = 0; kp < 4; kp++) {
    STEP(sA, 4 * kp)
    STEP(sB, 4 * kp + 1)
    STEP(sC, 4 * kp + 2)
    STEP(sD, 4 * kp + 3)
  }
#pragma unroll
  for (int reg = 0; reg < 4; reg++) {
    const int row = q * 4 + reg;
    const float li0 = invS[row], li1 = invS[16 + row];
    float v00 = acc00[reg] * li0, v01 = acc01[reg] * li0;
    float v10 = acc10[reg] * li1, v11 = acc11[reg] * li1;
    v00 = v00 > 0.f ? v00 : __expf(v00) - 1.f;
    v01 = v01 > 0.f ? v01 : __expf(v01) - 1.f;
    v10 = v10 > 0.f ? v10 : __expf(v10) - 1.f;
    v11 = v11 > 0.f ? v11 : __expf(v11) - 1.f;
    float* o0 = out + (base + i0 + row) * (long)ostride + ocoff + n0 + m16;
    float* o1 = out + (base + i0 + 16 + row) * (long)ostride + ocoff + n0 + m16;
    o0[0] = v00; o0[16] = v01;
    o1[0] = v10; o1[16] = v11;
  }
}

// ---- K3/K4: MFMA GEMM, C = A[32768,K] @ BT^T, 32 rows x 128 cols/block.
// A fp32 -> bf16 hi/lo during LDS staging; B fragment-order with even/odd
// named-register prefetch (round-17 pattern). MODE 0: emit whT (fragment
// order) + src/dst; blocks >=1024 do the Wc split (bias=Wc, outF=WcT_H).
// MODE 1: +bias +leaky fp32 store. ----

#define GLD(S, KB) \
  S##0H = *(const s16x8*)&bh0[(KB) * 512]; \
  S##0L = *(const s16x8*)&bl0[(KB) * 512]; \
  S##1H = *(const s16x8*)&bh0[K * 16 + (KB) * 512]; \
  S##1L = *(const s16x8*)&bl0[K * 16 + (KB) * 512];

#define GSTEP(S, KS) { \
  const int k0_ = (KS) * 32 + q * 8; \
  const s16x8 a0H_ = *(const s16x8*)&AsH[m16][k0_]; \
  const s16x8 a0L_ = *(const s16x8*)&AsL[m16][k0_]; \
  const s16x8 a1H_ = *(const s16x8*)&AsH[16 + m16][k0_]; \
  const s16x8 a1L_ = *(const s16x8*)&AsL[16 + m16][k0_]; \
  MF(a0H_, S##0H, acc[0][0]); MF(a0H_, S##1H, acc[0][1]); \
  MF(a1H_, S##0H, acc[1][0]); MF(a1H_, S##1H, acc[1][1]); \
  MF(a0L_, S##0H, acc[0][0]); MF(a0L_, S##1H, acc[0][1]); \
  MF(a1L_, S##0H, acc[1][0]); MF(a1L_, S##1H, acc[1][1]); \
  MF(a0H_, S##0L, acc[0][0]); MF(a0H_, S##1L, acc[0][1]); \
  MF(a1H_, S##0L, acc[1][0]); MF(a1H_, S##1L, acc[1][1]); }

template<int K, int KC, int MODE>
__global__ __launch_bounds__(256) void mfma_gemm(
    const float* __restrict__ A,
    const ushort* __restrict__ BTH, const ushort* __restrict__ BTL,
    const float* __restrict__ bias, float* __restrict__ outF,
    ushort* __restrict__ whtH, ushort* __restrict__ whtL,
    const float* __restrict__ avec, float* __restrict__ src, float* __restrict__ dst,
    const int ostride)
{
  constexpr int KP = KC + 8;
  __shared__ ushort AsH[32][KP];
  __shared__ ushort AsL[32][KP];
  __shared__ float sredS[4][32], sredD[4][32];
  const int t = threadIdx.x;

  if (MODE == 0 && blockIdx.x >= 1024) {
    // ---- folded wt_prep(Wc): [128,256] fp32 -> fragment-order WcT.
    // bias == Wc, outF == WcT_H (WcT_L contiguous at +32768).
    const int idx = ((int)blockIdx.x - 1024) * 256 + t;   // 32768 exact
    const int k = idx >> 8, n = idx & 255;
    const float v = bias[idx];
    const ushort h = bf16_rne(v);
    const long o = w_frag_off(n, k, 128);
    ushort* __restrict__ WcTH = (ushort*)outF;
    WcTH[o] = h;
    WcTH[32768 + o] = bf16_rne(v - bf16_tof(h));
    return;
  }

  const long row0 = (long)blockIdx.x * 32;
  const int ncoff = (MODE == 1) ? blockIdx.y * 128 : 0;

  const int wv = t >> 6, lane = t & 63;
  const int m16 = lane & 15, q = lane >> 4;
  const int n0 = wv * 32;
  // fragment-order B: tile (ncoff+n0)/16, lane*8; next 16-col tile at +K*16
  const ushort* __restrict__ bh0 = BTH + (long)((ncoff + n0) >> 4) * (K * 16) + lane * 8;
  const ushort* __restrict__ bl0 = BTL + (long)((ncoff + n0) >> 4) * (K * 16) + lane * 8;

  s16x8 gE0H, gE0L, gE1H, gE1L, gO0H, gO0L, gO1H, gO1L;
  GLD(gE, 0)
  GLD(gO, 1)

  f32x4 acc[2][2];
#pragma unroll
  for (int m = 0; m < 2; m++)
#pragma unroll
    for (int n = 0; n < 2; n++) acc[m][n] = (f32x4){0.f, 0.f, 0.f, 0.f};

#pragma unroll
  for (int kc = 0; kc < K; kc += KC) {
    constexpr int NIT = (32 * KC / 4) / 256;
#pragma unroll
    for (int it = 0; it < NIT; it++) {
      const int idx = t + it * 256;
      const int r = idx / (KC / 4), k4 = idx % (KC / 4);
      const float4 v = *(const float4*)&A[(row0 + r) * (long)K + kc + k4 * 4];
      split_store4(&AsH[r][k4 * 4], &AsL[r][k4 * 4], v.x, v.y, v.z, v.w);
    }
    __syncthreads();
#pragma unroll
    for (int ks2 = 0; ks2 < KC / 64; ks2++) {
      const int kbE = (kc >> 5) + 2 * ks2;
      GSTEP(gE, 2 * ks2)
      if (kbE + 2 < K / 32) { GLD(gE, kbE + 2) }
      GSTEP(gO, 2 * ks2 + 1)
      if (kbE + 3 < K / 32) { GLD(gO, kbE + 3) }
    }
    __syncthreads();
  }

  if (MODE == 0) {
    // whT hi/lo store in fragment order
    const long batch = row0 >> 9;
    const int iloc = (int)(row0 & 511);
#pragma unroll
    for (int m = 0; m < 2; m++)
#pragma unroll
      for (int n = 0; n < 2; n++) {
        const int c = n0 + n * 16 + m16;
        const int j = iloc + m * 16 + q * 4;        // j%4 == 0 -> contiguous 4
        const long o = wht_off(batch, c, j);
        const f32x4 v = acc[m][n];
        split_store4(&whtH[o], &whtL[o], v[0], v[1], v[2], v[3]);
      }
    // fused src/dst: reduce over cols (16 lanes x 2 n-tiles per wave, 4 waves)
    const float a10 = avec[n0 + m16], a11 = avec[n0 + 16 + m16];
    const float a20 = avec[128 + n0 + m16], a21 = avec[128 + n0 + 16 + m16];
#pragma unroll
    for (int m = 0; m < 2; m++) {
#pragma unroll
      for (int reg = 0; reg < 4; reg++) {
        float s = acc[m][0][reg] * a10 + acc[m][1][reg] * a11;
        float d = acc[m][0][reg] * a20 + acc[m][1][reg] * a21;
#pragma unroll
        for (int w = 1; w < 16; w <<= 1) {
          s += __shfl_xor(s, w, 64);
          d += __shfl_xor(d, w, 64);
        }
        if (m16 == 0) {
          const int row = m * 16 + q * 4 + reg;
          sredS[wv][row] = s;
          sredD[wv][row] = d;
        }
      }
    }
    __syncthreads();
    if (t < 32) {
      const float s = sredS[0][t] + sredS[1][t] + sredS[2][t] + sredS[3][t];
      const float d = sredD[0][t] + sredD[1][t] + sredD[2][t] + sredD[3][t];
      src[row0 + t] = s * LOG2E;   // log2-domain at producer
      dst[row0 + t] = d * LOG2E;
    }
  } else {
#pragma unroll
    for (int m = 0; m < 2; m++)
#pragma unroll
      for (int n = 0; n < 2; n++) {
        const int c = ncoff + n0 + n * 16 + m16;
        const float bv = bias[c];
#pragma unroll
        for (int reg = 0; reg < 4; reg++) {
          float v = acc[m][n][reg] + bv;
          v = fmaxf(v, ALPHA * v);
          outF[(row0 + m * 16 + q * 4 + reg) * (long)ostride + c] = v;
        }
      }
  }
}

extern "C" void kernel_launch(void* const* d_in, const int* in_sizes, int n_in,
                              void* d_out, int out_size, void* d_ws, size_t ws_size,
                              hipStream_t stream) {
  const float* compound = (const float*)d_in[0];
  const int*   adj      = (const int*)d_in[1];
  const float* W_stack  = (const float*)d_in[2];
  const float* a_stack  = (const float*)d_in[3];
  const float* W_out    = (const float*)d_in[4];
  const float* a_out    = (const float*)d_in[5];
  const float* Wc       = (const float*)d_in[6];
  const float* bc       = (const float*)d_in[7];
  float* out = (float*)d_out;

  // workspace: wht slots for 3 layers (48MB), then multi (50MB).
  // x aliases multi head. WcT lives in the DEAD layer-1 wht slot (slot 1 is
  // last read by the merged fused_attn; written by gemm384's extra blocks;
  // read only by the final GEMM).
  ushort* wht_all = (ushort*)d_ws;                    // 3 x 16MB slots
  float* f     = (float*)d_ws;
  float* multi = f + 12582912;                        // 12,582,912 floats
  float* x     = multi;                               // aliases multi head
  ushort* WcT_H = wht_all + WHT_SLOT;                 // dead slot-1 head
  ushort* WcT_L = WcT_H + 32768;                      // contiguous

  // d_out parking (dead until final GEMM overwrites):
  // mask 524288 uints | src[4] | dst[4] | WoT_H/L
  unsigned* mask = (unsigned*)d_out;
  float* doutF = (float*)d_out;
  float* srcB = doutF + 524288;                       // 4 x 32768
  float* dstB = srcB + 4 * 32768;                     // 4 x 32768
  ushort* WoT_H = (ushort*)(dstB + 4 * 32768);        // 98304 ushorts
  ushort* WoT_L = WoT_H + 98304;
  float* src3 = srcB + 3 * 32768;
  float* dst3 = dstB + 3 * 32768;

  // front: wh_small x3 + maskprep + wt_prep(W_out), INTERLEAVED, one dispatch
  front_union<<<5312, 256, 0, stream>>>(
      compound, W_stack, a_stack, wht_all, srcB, dstB,
      adj, mask, W_out, WoT_H, WoT_L);
  // 3 GAT heads
  fused_attn<<<dim3(16, 64, 3), 256, 0, stream>>>(
      mask, srcB, dstB, wht_all, multi, 384);
  // layer 4: Wh = multi @ W_out (MFMA, emits whT slot-0 + src/dst slot-3);
  // blocks >=1024 do the Wc split into slot-1 (bias=Wc, outF=WcT_H)
  mfma_gemm<384, 192, 0><<<1152, 256, 0, stream>>>(
      multi, WoT_H, WoT_L, Wc, (float*)WcT_H, wht_all, wht_all + 4194304,
      a_out, src3, dst3, 0);
  fused_attn<<<dim3(16, 64, 1), 256, 0, stream>>>(
      mask, src3, dst3, wht_all, x, 128);
  // final: out = leaky(x @ Wc + bc)  (MFMA, WcT from slot-1)
  mfma_gemm<128, 128, 1><<<dim3(1024, 2), 256, 0, stream>>>(
      x, WcT_H, WcT_L, bc, out, nullptr, nullptr, nullptr, nullptr, nullptr, 256);
}

// Round 14
// 223.871 us; speedup vs baseline: 1.0492x; 1.0492x over previous
//
#include <hip/hip_runtime.h>
#include <hip/hip_bf16.h>
#include <math.h>

// GAT predictor: B=64, N=512, ATOM=34, GAT=128, HID=256, 3 layers + out.
// Round-21: revert-and-keep after round-20's mixed result. KEEP: fused_attn
// entry-hoisted src/mask loads (48.2->47.0 proven) and the Wc-prep fold into
// the gemm384 dispatch (WcT in dead wht slot-1). REVERT: mfma_gemm's named-
// register B prefetch (cost ~6us — no launch_bounds floor, +32 VGPR dropped
// occupancy; prefetch can't span the __syncthreads() pairs anyway). B loads
// stay fragment-order coalesced; compiler pipelines within the barrier
// window. Bit-identical -> absmax 0.00390625.
// ws: wht[3] 48MB (slot1 hosts WcT after merged attn) | multi 50MB
// d_out: mask 2.1MB | src[4]/dst[4] 1MB | WoT 0.4MB  (until final GEMM)

#define ALPHA 0.2f
#define LOG2E 1.44269504088896f

#if __has_builtin(__builtin_amdgcn_exp2f)
#define EXP2F(x) __builtin_amdgcn_exp2f(x)
#else
extern "C" __device__ float __ocml_exp2_f32(float);
#define EXP2F(x) __ocml_exp2_f32(x)
#endif

typedef __attribute__((ext_vector_type(8))) short s16x8;   // 8 bf16 (4 VGPRs)
typedef __attribute__((ext_vector_type(4))) float f32x4;

#define MF(a, b, c) c = __builtin_amdgcn_mfma_f32_16x16x32_bf16(a, b, c, 0, 0, 0)

__device__ __forceinline__ ushort bf16_rne(float f) {
  union { float f; unsigned u; } v; v.f = f;
  unsigned r = v.u + 0x7FFFu + ((v.u >> 16) & 1u);
  return (ushort)(r >> 16);
}
__device__ __forceinline__ float bf16_tof(ushort h) {
  union { unsigned u; float f; } v; v.u = ((unsigned)h) << 16;
  return v.f;
}
__device__ __forceinline__ void split_store4(
    ushort* __restrict__ ph, ushort* __restrict__ pl,
    float v0, float v1, float v2, float v3) {
  ushort h0 = bf16_rne(v0), h1 = bf16_rne(v1), h2 = bf16_rne(v2), h3 = bf16_rne(v3);
  *(ushort4*)ph = make_ushort4(h0, h1, h2, h3);
  *(ushort4*)pl = make_ushort4(bf16_rne(v0 - bf16_tof(h0)), bf16_rne(v1 - bf16_tof(h1)),
                               bf16_rne(v2 - bf16_tof(h2)), bf16_rne(v3 - bf16_tof(h3)));
}

// wht fragment-order offset (K=512): batch*65536 + (col/16)*8192 + (j/32)*512
//   + (col%16)*8 + ((j>>3)&3)*128 + (j&7)   [j = node index = GEMM k]
__device__ __forceinline__ long wht_off(long batch, int c, int j) {
  return batch * 65536 + (long)(c >> 4) * 8192 + (j >> 5) * 512 +
         ((c & 15) << 3) + (((j >> 3) & 3) << 7) + (j & 7);
}

// generic fragment-order offset for a [Kd x Nd] weight (col c, k-index j)
__device__ __forceinline__ long w_frag_off(int c, int j, int Kd) {
  return (long)(c >> 4) * (Kd * 16) + (j >> 5) * 512 +
         ((c & 15) << 3) + (((j >> 3) & 3) << 7) + (j & 7);
}

#define WHT_SLOT 8388608L   // ushorts per layer slot (whtH 4M + whtL 4M)

// ---- K0 (front union, INTERLEAVED): per 83-block group: 48 wh | 32 mask |
// 3 wt(W_out). Resident windows carry the global mix -> mask's HBM stream
// overlaps wh's compute. ----
__global__ __launch_bounds__(256) void front_union(
    const float* __restrict__ A, const float* __restrict__ Wst,
    const float* __restrict__ ast,
    ushort* __restrict__ whtBase, float* __restrict__ srcB, float* __restrict__ dstB,
    const int* __restrict__ adj, unsigned* __restrict__ mask,
    const float* __restrict__ W_out, ushort* __restrict__ WoT_H, ushort* __restrict__ WoT_L)
{
  __shared__ float AsT[34][36];
  __shared__ float Ws[34][128];
  const int t = threadIdx.x;
  const int g = blockIdx.x / 83, r83 = blockIdx.x - g * 83;

  if (r83 >= 48) {
    if (r83 < 80) {
      // ---- maskprep: pack adj>0 into bitmask [32768][16] uint ----
      const int mb = g * 32 + (r83 - 48);           // [0,2048)
      const int gid = mb * 256 + t;
      const int4* __restrict__ p = (const int4*)(adj + (long)gid * 32);
      unsigned m = 0;
#pragma unroll
      for (int k = 0; k < 8; k++) {
        const int4 v = p[k];
        m |= (v.x > 0 ? 1u : 0u) << (4 * k);
        m |= (v.y > 0 ? 1u : 0u) << (4 * k + 1);
        m |= (v.z > 0 ? 1u : 0u) << (4 * k + 2);
        m |= (v.w > 0 ? 1u : 0u) << (4 * k + 3);
      }
      mask[gid] = m;
    } else {
      // ---- wt_prep(W_out): [384,128] fp32 -> fragment-order WoT ----
      const int wb = g * 3 + (r83 - 80);            // [0,192)
      const int idx = wb * 256 + t;                 // 49152 exact
      const int k = idx / 128, n = idx % 128;
      const float v = W_out[idx];
      const ushort h = bf16_rne(v);
      const long o = w_frag_off(n, k, 384);
      WoT_H[o] = h;
      WoT_L[o] = bf16_rne(v - bf16_tof(h));
    }
    return;
  }

  // ---- wh_small: Wh_l = compound @ W_l -> whT_l (fragment order) + src/dst
  const int bid = g * 48 + r83;                     // [0,3072)
  const int l = bid >> 10;
  const float* __restrict__ W = Wst + (long)l * 34 * 128;
  const float* __restrict__ avec = ast + (long)l * 256;
  ushort* __restrict__ whtH = whtBase + (long)l * WHT_SLOT;
  ushort* __restrict__ whtL = whtH + 4194304;
  float* __restrict__ src = srcB + (long)l * 32768;
  float* __restrict__ dst = dstB + (long)l * 32768;
  const long row0 = (long)(bid & 1023) * 32;
  const int cg = t & 31, rg = t >> 5;
  {
    const int r = t >> 3, l8 = t & 7;
#pragma unroll
    for (int q = 0; q < 5; q++) {
      int k = l8 + q * 8;
      if (k < 34) AsT[k][r] = A[(row0 + r) * 34 + k];
    }
  }
  {
    int idx = t;
#pragma unroll
    for (int i = 0; i < 17; i++, idx += 256)
      Ws[idx >> 7][idx & 127] = W[idx];
  }
  __syncthreads();

  float acc[4][4];
#pragma unroll
  for (int r = 0; r < 4; r++)
#pragma unroll
    for (int c = 0; c < 4; c++) acc[r][c] = 0.f;
#pragma unroll 2
  for (int k = 0; k < 34; k++) {
    const float4 wv = *(const float4*)&Ws[k][cg * 4];
    const float4 av = *(const float4*)&AsT[k][rg * 4];
#define GFMA(r, a) \
    acc[r][0] += (a) * wv.x; acc[r][1] += (a) * wv.y; \
    acc[r][2] += (a) * wv.z; acc[r][3] += (a) * wv.w;
    GFMA(0, av.x) GFMA(1, av.y) GFMA(2, av.z) GFMA(3, av.w)
#undef GFMA
  }

  {
    const long batch = row0 >> 9;
    const int j = (int)(row0 & 511) + rg * 4;       // j%4 == 0 -> contiguous 4
#pragma unroll
    for (int cc = 0; cc < 4; cc++) {
      const long o = wht_off(batch, cg * 4 + cc, j);
      split_store4(&whtH[o], &whtL[o], acc[0][cc], acc[1][cc], acc[2][cc], acc[3][cc]);
    }
  }

  const float4 a1 = *(const float4*)&avec[cg * 4];
  const float4 a2 = *(const float4*)&avec[128 + cg * 4];
#pragma unroll
  for (int r = 0; r < 4; r++) {
    float s = acc[r][0]*a1.x + acc[r][1]*a1.y + acc[r][2]*a1.z + acc[r][3]*a1.w;
    float d = acc[r][0]*a2.x + acc[r][1]*a2.y + acc[r][2]*a2.z + acc[r][3]*a2.w;
#pragma unroll
    for (int w = 1; w < 32; w <<= 1) {
      s += __shfl_xor(s, w, 64);
      d += __shfl_xor(d, w, 64);
    }
    if (cg == 0) {
      src[row0 + rg * 4 + r] = s * LOG2E;   // log2-domain at producer
      dst[row0 + rg * 4 + r] = d * LOG2E;
    }
  }
}

// ---- K2 (fused, multi-layer): single-pass masked softmax -> LDS As
// (unnormalized bf16 p), then out = elu((P @ WhT^T) * 1/rowsum).
// blockIdx.z = layer. B prefetch: depth-4 named-register ping-pong;
// src/mask loads hoisted to entry. ----

#define LD_SET(S, KB) \
  S##0H = *(const s16x8*)&bH[(KB) * 512]; \
  S##0L = *(const s16x8*)&bL[(KB) * 512]; \
  S##1H = *(const s16x8*)&bH[8192 + (KB) * 512]; \
  S##1L = *(const s16x8*)&bL[8192 + (KB) * 512];

#define STEP(S, KB) { \
  const int k0_ = ((KB) * 32 + q * 8) ^ ((((KB) >> 1) & 7) << 3); \
  const s16x8 a0_ = *(const s16x8*)&As[m16][k0_]; \
  const s16x8 a1_ = *(const s16x8*)&As[16 + m16][k0_]; \
  MF(a0_, S##0H, acc00); MF(a0_, S##1H, acc01); \
  MF(a1_, S##0H, acc10); MF(a1_, S##1H, acc11); \
  MF(a0_, S##0L, acc00); MF(a0_, S##1L, acc01); \
  MF(a1_, S##0L, acc10); MF(a1_, S##1L, acc11); \
  if ((KB) + 4 < 16) { LD_SET(S, (KB) + 4) } }

__global__ __launch_bounds__(256, 4) void fused_attn(
    const unsigned* __restrict__ mask,
    const float* __restrict__ srcB, const float* __restrict__ dstB,
    const ushort* __restrict__ whtBase,
    float* __restrict__ out, const int ostride)
{
  __shared__ ushort As[32][520];
  __shared__ float dstS[544];          // phys = j + (j>>6)*4
  __shared__ float invS[32];
  __shared__ float wredM[4];
  const int t = threadIdx.x;
  const int l = blockIdx.z;
  const float* __restrict__ src = srcB + (long)l * 32768;
  const float* __restrict__ dstv = dstB + (long)l * 32768;
  const ushort* __restrict__ whtH = whtBase + (long)l * WHT_SLOT;
  const ushort* __restrict__ whtL = whtH + 4194304;
  const int ocoff = l * 128;
  // XCD swizzle: per layer 1024 blocks = 8 XCDs x 128; each XCD gets 8 whole
  // batches so a batch's 512KB wht slice is HBM-fetched once, reused via L2.
  const int flat = blockIdx.y * 16 + blockIdx.x;
  const int swz = (flat & 7) * 128 + (flat >> 3);
  const long base = (long)(swz >> 4) * 512;   // batch * 512
  const int i0 = (swz & 15) * 32;             // row tile within batch

  // MFMA geometry + entry prefetch of k-blocks 0..3 + phase-1 global inputs
  // (all independent of the dstS barrier; latency hides under staging).
  const int wv = t >> 6, lane = t & 63;
  const int m16 = lane & 15, q = lane >> 4;
  const int n0 = wv * 32;
  const ushort* __restrict__ bH = whtH + base * 128 + wv * 16384 + lane * 8;
  const ushort* __restrict__ bL = whtL + base * 128 + wv * 16384 + lane * 8;
  s16x8 sA0H, sA0L, sA1H, sA1L, sB0H, sB0L, sB1H, sB1L;
  s16x8 sC0H, sC0L, sC1H, sC1L, sD0H, sD0L, sD1H, sD1L;
  LD_SET(sA, 0)
  LD_SET(sB, 1)
  LD_SET(sC, 2)
  LD_SET(sD, 3)
  const int r1 = t >> 3, l8 = t & 7;
  const long irow = base + i0 + r1;
  const float si = src[irow];
  const uint2 mw2 = *(const uint2*)(mask + irow * 16 + 2 * l8);

  // stage dstS (already log2 domain, padded layout) + block-wide max md
  {
    const float d0 = dstv[base + t];
    const float d1 = dstv[base + t + 256];
    dstS[t + (t >> 6) * 4] = d0;
    const int t2 = t + 256;
    dstS[t2 + (t2 >> 6) * 4] = d1;
    float mx = fmaxf(d0, d1);
#pragma unroll
    for (int w = 1; w < 64; w <<= 1) mx = fmaxf(mx, __shfl_xor(mx, w, 64));
    if ((t & 63) == 0) wredM[t >> 6] = mx;
  }
  __syncthreads();
  const float md = fmaxf(fmaxf(wredM[0], wredM[1]), fmaxf(wredM[2], wredM[3]));

  // ---- phase 1: single-pass masked softmax -> As bf16, invS = 1/rowsum.
  // 8 threads per row, thread l8 owns contiguous j in [l8*64, l8*64+64).
  {
    const float em = si + md;
    const float m = fmaxf(em, ALPHA * em);   // >= masked max of leaky(si+dv)
    const float* __restrict__ dp = &dstS[l8 * 68];
    const int jb = l8 * 64;
    const int xs = l8 << 3;                  // As column XOR swizzle
    float sum = 0.f;
#pragma unroll
    for (int g = 0; g < 16; g++) {
      const float4 dv = *(const float4*)&dp[g * 4];
      const unsigned w = ((g & 8) ? mw2.y : mw2.x) >> ((g & 7) * 4);
      float e0 = si + dv.x, e1 = si + dv.y, e2 = si + dv.z, e3 = si + dv.w;
      e0 = fmaxf(e0, ALPHA * e0) - m; e1 = fmaxf(e1, ALPHA * e1) - m;
      e2 = fmaxf(e2, ALPHA * e2) - m; e3 = fmaxf(e3, ALPHA * e3) - m;
      float p0 = EXP2F(e0), p1 = EXP2F(e1), p2 = EXP2F(e2), p3 = EXP2F(e3);
      p0 = (w & 1u) ? p0 : 0.f;
      p1 = (w & 2u) ? p1 : 0.f;
      p2 = (w & 4u) ? p2 : 0.f;
      p3 = (w & 8u) ? p3 : 0.f;
      sum += (p0 + p1) + (p2 + p3);
      union { __hip_bfloat162 b; unsigned u; } u01, u23;
      u01.b = __float22bfloat162_rn(make_float2(p0, p1));
      u23.b = __float22bfloat162_rn(make_float2(p2, p3));
      *(uint2*)&As[r1][(jb + g * 4) ^ xs] = make_uint2(u01.u, u23.u);
    }
#pragma unroll
    for (int w = 1; w < 8; w <<= 1) sum += __shfl_xor(sum, w, 64);
    if (l8 == 0) invS[r1] = 1.f / sum;
  }
  __syncthreads();

  // ---- phase 2: MFMA aggregation, depth-4 named-register ping-pong.
  // As reads apply the same column XOR: ((kb>>1)&7)<<3, compile-time. ----
  f32x4 acc00 = {0.f,0.f,0.f,0.f}, acc01 = {0.f,0.f,0.f,0.f};
  f32x4 acc10 = {0.f,0.f,0.f,0.f}, acc11 = {0.f,0.f,0.f,0.f};
#pragma unroll
  for (int kp = 0; kp < 4; kp++) {
    STEP(sA, 4 * kp)
    STEP(sB, 4 * kp + 1)
    STEP(sC, 4 * kp + 2)
    STEP(sD, 4 * kp + 3)
  }
#pragma unroll
  for (int reg = 0; reg < 4; reg++) {
    const int row = q * 4 + reg;
    const float li0 = invS[row], li1 = invS[16 + row];
    float v00 = acc00[reg] * li0, v01 = acc01[reg] * li0;
    float v10 = acc10[reg] * li1, v11 = acc11[reg] * li1;
    v00 = v00 > 0.f ? v00 : __expf(v00) - 1.f;
    v01 = v01 > 0.f ? v01 : __expf(v01) - 1.f;
    v10 = v10 > 0.f ? v10 : __expf(v10) - 1.f;
    v11 = v11 > 0.f ? v11 : __expf(v11) - 1.f;
    float* o0 = out + (base + i0 + row) * (long)ostride + ocoff + n0 + m16;
    float* o1 = out + (base + i0 + 16 + row) * (long)ostride + ocoff + n0 + m16;
    o0[0] = v00; o0[16] = v01;
    o1[0] = v10; o1[16] = v11;
  }
}

// ---- K3/K4: MFMA GEMM, C = A[32768,K] @ BT^T, 32 rows x 128 cols/block.
// A fp32 -> bf16 hi/lo during LDS staging; B fragment-order (coalesced 1KB
// loads; round-19 inner loop — no named prefetch, compiler pipelines).
// MODE 0: emit whT (fragment order) + src/dst; blocks >=1024 do the Wc
// split (bias=Wc, outF=WcT_H). MODE 1: +bias +leaky fp32 store. ----
template<int K, int KC, int MODE>
__global__ __launch_bounds__(256) void mfma_gemm(
    const float* __restrict__ A,
    const ushort* __restrict__ BTH, const ushort* __restrict__ BTL,
    const float* __restrict__ bias, float* __restrict__ outF,
    ushort* __restrict__ whtH, ushort* __restrict__ whtL,
    const float* __restrict__ avec, float* __restrict__ src, float* __restrict__ dst,
    const int ostride)
{
  constexpr int KP = KC + 8;
  __shared__ ushort AsH[32][KP];
  __shared__ ushort AsL[32][KP];
  __shared__ float sredS[4][32], sredD[4][32];
  const int t = threadIdx.x;

  if (MODE == 0 && blockIdx.x >= 1024) {
    // ---- folded wt_prep(Wc): [128,256] fp32 -> fragment-order WcT.
    // bias == Wc, outF == WcT_H (WcT_L contiguous at +32768).
    const int idx = ((int)blockIdx.x - 1024) * 256 + t;   // 32768 exact
    const int k = idx >> 8, n = idx & 255;
    const float v = bias[idx];
    const ushort h = bf16_rne(v);
    const long o = w_frag_off(n, k, 128);
    ushort* __restrict__ WcTH = (ushort*)outF;
    WcTH[o] = h;
    WcTH[32768 + o] = bf16_rne(v - bf16_tof(h));
    return;
  }

  const long row0 = (long)blockIdx.x * 32;
  const int ncoff = (MODE == 1) ? blockIdx.y * 128 : 0;

  const int wv = t >> 6, lane = t & 63;
  const int m16 = lane & 15, q = lane >> 4;
  const int n0 = wv * 32;
  // fragment-order B: tile (ncoff+n0)/16, lane*8; next 16-col tile at +K*16
  const ushort* __restrict__ bh0 = BTH + (long)((ncoff + n0) >> 4) * (K * 16) + lane * 8;
  const ushort* __restrict__ bl0 = BTL + (long)((ncoff + n0) >> 4) * (K * 16) + lane * 8;

  f32x4 acc[2][2];
#pragma unroll
  for (int m = 0; m < 2; m++)
#pragma unroll
    for (int n = 0; n < 2; n++) acc[m][n] = (f32x4){0.f, 0.f, 0.f, 0.f};

  for (int kc = 0; kc < K; kc += KC) {
    constexpr int NIT = (32 * KC / 4) / 256;
#pragma unroll
    for (int it = 0; it < NIT; it++) {
      const int idx = t + it * 256;
      const int r = idx / (KC / 4), k4 = idx % (KC / 4);
      const float4 v = *(const float4*)&A[(row0 + r) * (long)K + kc + k4 * 4];
      split_store4(&AsH[r][k4 * 4], &AsL[r][k4 * 4], v.x, v.y, v.z, v.w);
    }
    __syncthreads();
#pragma unroll
    for (int ks = 0; ks < KC / 32; ks++) {
      const int k0 = ks * 32 + q * 8;
      const s16x8 a0H = *(const s16x8*)&AsH[m16][k0];
      const s16x8 a0L = *(const s16x8*)&AsL[m16][k0];
      const s16x8 a1H = *(const s16x8*)&AsH[16 + m16][k0];
      const s16x8 a1L = *(const s16x8*)&AsL[16 + m16][k0];
      const int bo = ((kc >> 5) + ks) * 512;
      const s16x8 b0H = *(const s16x8*)&bh0[bo];
      const s16x8 b0L = *(const s16x8*)&bl0[bo];
      const s16x8 b1H = *(const s16x8*)&bh0[K * 16 + bo];
      const s16x8 b1L = *(const s16x8*)&bl0[K * 16 + bo];
      acc[0][0] = __builtin_amdgcn_mfma_f32_16x16x32_bf16(a0H, b0H, acc[0][0], 0, 0, 0);
      acc[0][1] = __builtin_amdgcn_mfma_f32_16x16x32_bf16(a0H, b1H, acc[0][1], 0, 0, 0);
      acc[1][0] = __builtin_amdgcn_mfma_f32_16x16x32_bf16(a1H, b0H, acc[1][0], 0, 0, 0);
      acc[1][1] = __builtin_amdgcn_mfma_f32_16x16x32_bf16(a1H, b1H, acc[1][1], 0, 0, 0);
      acc[0][0] = __builtin_amdgcn_mfma_f32_16x16x32_bf16(a0L, b0H, acc[0][0], 0, 0, 0);
      acc[0][1] = __builtin_amdgcn_mfma_f32_16x16x32_bf16(a0L, b1H, acc[0][1], 0, 0, 0);
      acc[1][0] = __builtin_amdgcn_mfma_f32_16x16x32_bf16(a1L, b0H, acc[1][0], 0, 0, 0);
      acc[1][1] = __builtin_amdgcn_mfma_f32_16x16x32_bf16(a1L, b1H, acc[1][1], 0, 0, 0);
      acc[0][0] = __builtin_amdgcn_mfma_f32_16x16x32_bf16(a0H, b0L, acc[0][0], 0, 0, 0);
      acc[0][1] = __builtin_amdgcn_mfma_f32_16x16x32_bf16(a0H, b1L, acc[0][1], 0, 0, 0);
      acc[1][0] = __builtin_amdgcn_mfma_f32_16x16x32_bf16(a1H, b0L, acc[1][0], 0, 0, 0);
      acc[1][1] = __builtin_amdgcn_mfma_f32_16x16x32_bf16(a1H, b1L, acc[1][1], 0, 0, 0);
    }
    __syncthreads();
  }

  if (MODE == 0) {
    // whT hi/lo store in fragment order
    const long batch = row0 >> 9;
    const int iloc = (int)(row0 & 511);
#pragma unroll
    for (int m = 0; m < 2; m++)
#pragma unroll
      for (int n = 0; n < 2; n++) {
        const int c = n0 + n * 16 + m16;
        const int j = iloc + m * 16 + q * 4;        // j%4 == 0 -> contiguous 4
        const long o = wht_off(batch, c, j);
        const f32x4 v = acc[m][n];
        split_store4(&whtH[o], &whtL[o], v[0], v[1], v[2], v[3]);
      }
    // fused src/dst: reduce over cols (16 lanes x 2 n-tiles per wave, 4 waves)
    const float a10 = avec[n0 + m16], a11 = avec[n0 + 16 + m16];
    const float a20 = avec[128 + n0 + m16], a21 = avec[128 + n0 + 16 + m16];
#pragma unroll
    for (int m = 0; m < 2; m++) {
#pragma unroll
      for (int reg = 0; reg < 4; reg++) {
        float s = acc[m][0][reg] * a10 + acc[m][1][reg] * a11;
        float d = acc[m][0][reg] * a20 + acc[m][1][reg] * a21;
#pragma unroll
        for (int w = 1; w < 16; w <<= 1) {
          s += __shfl_xor(s, w, 64);
          d += __shfl_xor(d, w, 64);
        }
        if (m16 == 0) {
          const int row = m * 16 + q * 4 + reg;
          sredS[wv][row] = s;
          sredD[wv][row] = d;
        }
      }
    }
    __syncthreads();
    if (t < 32) {
      const float s = sredS[0][t] + sredS[1][t] + sredS[2][t] + sredS[3][t];
      const float d = sredD[0][t] + sredD[1][t] + sredD[2][t] + sredD[3][t];
      src[row0 + t] = s * LOG2E;   // log2-domain at producer
      dst[row0 + t] = d * LOG2E;
    }
  } else {
#pragma unroll
    for (int m = 0; m < 2; m++)
#pragma unroll
      for (int n = 0; n < 2; n++) {
        const int c = ncoff + n0 + n * 16 + m16;
        const float bv = bias[c];
#pragma unroll
        for (int reg = 0; reg < 4; reg++) {
          float v = acc[m][n][reg] + bv;
          v = fmaxf(v, ALPHA * v);
          outF[(row0 + m * 16 + q * 4 + reg) * (long)ostride + c] = v;
        }
      }
  }
}

extern "C" void kernel_launch(void* const* d_in, const int* in_sizes, int n_in,
                              void* d_out, int out_size, void* d_ws, size_t ws_size,
                              hipStream_t stream) {
  const float* compound = (const float*)d_in[0];
  const int*   adj      = (const int*)d_in[1];
  const float* W_stack  = (const float*)d_in[2];
  const float* a_stack  = (const float*)d_in[3];
  const float* W_out    = (const float*)d_in[4];
  const float* a_out    = (const float*)d_in[5];
  const float* Wc       = (const float*)d_in[6];
  const float* bc       = (const float*)d_in[7];
  float* out = (float*)d_out;

  // workspace: wht slots for 3 layers (48MB), then multi (50MB).
  // x aliases multi head. WcT lives in the DEAD layer-1 wht slot (slot 1 is
  // last read by the merged fused_attn; written by gemm384's extra blocks;
  // read only by the final GEMM).
  ushort* wht_all = (ushort*)d_ws;                    // 3 x 16MB slots
  float* f     = (float*)d_ws;
  float* multi = f + 12582912;                        // 12,582,912 floats
  float* x     = multi;                               // aliases multi head
  ushort* WcT_H = wht_all + WHT_SLOT;                 // dead slot-1 head
  ushort* WcT_L = WcT_H + 32768;                      // contiguous

  // d_out parking (dead until final GEMM overwrites):
  // mask 524288 uints | src[4] | dst[4] | WoT_H/L
  unsigned* mask = (unsigned*)d_out;
  float* doutF = (float*)d_out;
  float* srcB = doutF + 524288;                       // 4 x 32768
  float* dstB = srcB + 4 * 32768;                     // 4 x 32768
  ushort* WoT_H = (ushort*)(dstB + 4 * 32768);        // 98304 ushorts
  ushort* WoT_L = WoT_H + 98304;
  float* src3 = srcB + 3 * 32768;
  float* dst3 = dstB + 3 * 32768;

  // front: wh_small x3 + maskprep + wt_prep(W_out), INTERLEAVED, one dispatch
  front_union<<<5312, 256, 0, stream>>>(
      compound, W_stack, a_stack, wht_all, srcB, dstB,
      adj, mask, W_out, WoT_H, WoT_L);
  // 3 GAT heads
  fused_attn<<<dim3(16, 64, 3), 256, 0, stream>>>(
      mask, srcB, dstB, wht_all, multi, 384);
  // layer 4: Wh = multi @ W_out (MFMA, emits whT slot-0 + src/dst slot-3);
  // blocks >=1024 do the Wc split into slot-1 (bias=Wc, outF=WcT_H)
  mfma_gemm<384, 192, 0><<<1152, 256, 0, stream>>>(
      multi, WoT_H, WoT_L, Wc, (float*)WcT_H, wht_all, wht_all + 4194304,
      a_out, src3, dst3, 0);
  fused_attn<<<dim3(16, 64, 1), 256, 0, stream>>>(
      mask, src3, dst3, wht_all, x, 128);
  // final: out = leaky(x @ Wc + bc)  (MFMA, WcT from slot-1)
  mfma_gemm<128, 128, 1><<<dim3(1024, 2), 256, 0, stream>>>(
      x, WcT_H, WcT_L, bc, out, nullptr, nullptr, nullptr, nullptr, nullptr, 256);
}

// Round 15
// 221.017 us; speedup vs baseline: 1.0628x; 1.0129x over previous
//
#include <hip/hip_runtime.h>
#include <hip/hip_bf16.h>
#include <math.h>

// GAT predictor: B=64, N=512, ATOM=34, GAT=128, HID=256, 3 layers + out.
// Round-22: final GEMM fused into layer-4 fused_attn. Each layer-4 block
// produces a complete 32x128 x-tile (= the final GEMM's whole K range for
// its rows), so the epilogue splits x to bf16 H/L in-register, stages into
// the existing As LDS, barriers, and runs x@WcT^T (+bc, leaky) -> d_out in
// the same block (3-term hi/lo, same per-acc add order -> bit-exact).
// Removes the final dispatch + gap + 33.6MB x round-trip. d_out race fixed:
// gemm384 gets 128 copy-blocks moving mask into dead wht slot-1 (src3/dst3
// also redirected there), so the FINAL kernel reads only ws, writes only
// d_out. 4 dispatches total.
// ws: wht[3] 48MB; slot-1 after merged attn hosts: WcT 128KB | mask copy
//     2MB | src3/dst3 256KB. multi 50MB.
// d_out: mask 2.1MB | WoT 0.4MB parked until gemm384 done; FINAL overwrites.

#define ALPHA 0.2f
#define LOG2E 1.44269504088896f

#if __has_builtin(__builtin_amdgcn_exp2f)
#define EXP2F(x) __builtin_amdgcn_exp2f(x)
#else
extern "C" __device__ float __ocml_exp2_f32(float);
#define EXP2F(x) __ocml_exp2_f32(x)
#endif

typedef __attribute__((ext_vector_type(8))) short s16x8;   // 8 bf16 (4 VGPRs)
typedef __attribute__((ext_vector_type(4))) float f32x4;

#define MF(a, b, c) c = __builtin_amdgcn_mfma_f32_16x16x32_bf16(a, b, c, 0, 0, 0)

__device__ __forceinline__ ushort bf16_rne(float f) {
  union { float f; unsigned u; } v; v.f = f;
  unsigned r = v.u + 0x7FFFu + ((v.u >> 16) & 1u);
  return (ushort)(r >> 16);
}
__device__ __forceinline__ float bf16_tof(ushort h) {
  union { unsigned u; float f; } v; v.u = ((unsigned)h) << 16;
  return v.f;
}
__device__ __forceinline__ void split_store4(
    ushort* __restrict__ ph, ushort* __restrict__ pl,
    float v0, float v1, float v2, float v3) {
  ushort h0 = bf16_rne(v0), h1 = bf16_rne(v1), h2 = bf16_rne(v2), h3 = bf16_rne(v3);
  *(ushort4*)ph = make_ushort4(h0, h1, h2, h3);
  *(ushort4*)pl = make_ushort4(bf16_rne(v0 - bf16_tof(h0)), bf16_rne(v1 - bf16_tof(h1)),
                               bf16_rne(v2 - bf16_tof(h2)), bf16_rne(v3 - bf16_tof(h3)));
}

// wht fragment-order offset (K=512): batch*65536 + (col/16)*8192 + (j/32)*512
//   + (col%16)*8 + ((j>>3)&3)*128 + (j&7)   [j = node index = GEMM k]
__device__ __forceinline__ long wht_off(long batch, int c, int j) {
  return batch * 65536 + (long)(c >> 4) * 8192 + (j >> 5) * 512 +
         ((c & 15) << 3) + (((j >> 3) & 3) << 7) + (j & 7);
}

// generic fragment-order offset for a [Kd x Nd] weight (col c, k-index j)
__device__ __forceinline__ long w_frag_off(int c, int j, int Kd) {
  return (long)(c >> 4) * (Kd * 16) + (j >> 5) * 512 +
         ((c & 15) << 3) + (((j >> 3) & 3) << 7) + (j & 7);
}

#define WHT_SLOT 8388608L   // ushorts per layer slot (whtH 4M + whtL 4M)

// ---- K0 (front union, INTERLEAVED): per 83-block group: 48 wh | 32 mask |
// 3 wt(W_out). Resident windows carry the global mix -> mask's HBM stream
// overlaps wh's compute. ----
__global__ __launch_bounds__(256) void front_union(
    const float* __restrict__ A, const float* __restrict__ Wst,
    const float* __restrict__ ast,
    ushort* __restrict__ whtBase, float* __restrict__ srcB, float* __restrict__ dstB,
    const int* __restrict__ adj, unsigned* __restrict__ mask,
    const float* __restrict__ W_out, ushort* __restrict__ WoT_H, ushort* __restrict__ WoT_L)
{
  __shared__ float AsT[34][36];
  __shared__ float Ws[34][128];
  const int t = threadIdx.x;
  const int g = blockIdx.x / 83, r83 = blockIdx.x - g * 83;

  if (r83 >= 48) {
    if (r83 < 80) {
      // ---- maskprep: pack adj>0 into bitmask [32768][16] uint ----
      const int mb = g * 32 + (r83 - 48);           // [0,2048)
      const int gid = mb * 256 + t;
      const int4* __restrict__ p = (const int4*)(adj + (long)gid * 32);
      unsigned m = 0;
#pragma unroll
      for (int k = 0; k < 8; k++) {
        const int4 v = p[k];
        m |= (v.x > 0 ? 1u : 0u) << (4 * k);
        m |= (v.y > 0 ? 1u : 0u) << (4 * k + 1);
        m |= (v.z > 0 ? 1u : 0u) << (4 * k + 2);
        m |= (v.w > 0 ? 1u : 0u) << (4 * k + 3);
      }
      mask[gid] = m;
    } else {
      // ---- wt_prep(W_out): [384,128] fp32 -> fragment-order WoT ----
      const int wb = g * 3 + (r83 - 80);            // [0,192)
      const int idx = wb * 256 + t;                 // 49152 exact
      const int k = idx / 128, n = idx % 128;
      const float v = W_out[idx];
      const ushort h = bf16_rne(v);
      const long o = w_frag_off(n, k, 384);
      WoT_H[o] = h;
      WoT_L[o] = bf16_rne(v - bf16_tof(h));
    }
    return;
  }

  // ---- wh_small: Wh_l = compound @ W_l -> whT_l (fragment order) + src/dst
  const int bid = g * 48 + r83;                     // [0,3072)
  const int l = bid >> 10;
  const float* __restrict__ W = Wst + (long)l * 34 * 128;
  const float* __restrict__ avec = ast + (long)l * 256;
  ushort* __restrict__ whtH = whtBase + (long)l * WHT_SLOT;
  ushort* __restrict__ whtL = whtH + 4194304;
  float* __restrict__ src = srcB + (long)l * 32768;
  float* __restrict__ dst = dstB + (long)l * 32768;
  const long row0 = (long)(bid & 1023) * 32;
  const int cg = t & 31, rg = t >> 5;
  {
    const int r = t >> 3, l8 = t & 7;
#pragma unroll
    for (int q = 0; q < 5; q++) {
      int k = l8 + q * 8;
      if (k < 34) AsT[k][r] = A[(row0 + r) * 34 + k];
    }
  }
  {
    int idx = t;
#pragma unroll
    for (int i = 0; i < 17; i++, idx += 256)
      Ws[idx >> 7][idx & 127] = W[idx];
  }
  __syncthreads();

  float acc[4][4];
#pragma unroll
  for (int r = 0; r < 4; r++)
#pragma unroll
    for (int c = 0; c < 4; c++) acc[r][c] = 0.f;
#pragma unroll 2
  for (int k = 0; k < 34; k++) {
    const float4 wv = *(const float4*)&Ws[k][cg * 4];
    const float4 av = *(const float4*)&AsT[k][rg * 4];
#define GFMA(r, a) \
    acc[r][0] += (a) * wv.x; acc[r][1] += (a) * wv.y; \
    acc[r][2] += (a) * wv.z; acc[r][3] += (a) * wv.w;
    GFMA(0, av.x) GFMA(1, av.y) GFMA(2, av.z) GFMA(3, av.w)
#undef GFMA
  }

  {
    const long batch = row0 >> 9;
    const int j = (int)(row0 & 511) + rg * 4;       // j%4 == 0 -> contiguous 4
#pragma unroll
    for (int cc = 0; cc < 4; cc++) {
      const long o = wht_off(batch, cg * 4 + cc, j);
      split_store4(&whtH[o], &whtL[o], acc[0][cc], acc[1][cc], acc[2][cc], acc[3][cc]);
    }
  }

  const float4 a1 = *(const float4*)&avec[cg * 4];
  const float4 a2 = *(const float4*)&avec[128 + cg * 4];
#pragma unroll
  for (int r = 0; r < 4; r++) {
    float s = acc[r][0]*a1.x + acc[r][1]*a1.y + acc[r][2]*a1.z + acc[r][3]*a1.w;
    float d = acc[r][0]*a2.x + acc[r][1]*a2.y + acc[r][2]*a2.z + acc[r][3]*a2.w;
#pragma unroll
    for (int w = 1; w < 32; w <<= 1) {
      s += __shfl_xor(s, w, 64);
      d += __shfl_xor(d, w, 64);
    }
    if (cg == 0) {
      src[row0 + rg * 4 + r] = s * LOG2E;   // log2-domain at producer
      dst[row0 + rg * 4 + r] = d * LOG2E;
    }
  }
}

// ---- K2 (fused, multi-layer): single-pass masked softmax -> LDS As
// (unnormalized bf16 p), then out = elu((P @ WhT^T) * 1/rowsum).
// blockIdx.z = layer. B prefetch: depth-4 named-register ping-pong;
// src/mask loads hoisted to entry. FINAL=1: instead of writing x, split it
// to bf16 H/L into As, barrier, and run x@WcT^T (+bc, leaky) -> out. ----

#define LD_SET(S, KB) \
  S##0H = *(const s16x8*)&bH[(KB) * 512]; \
  S##0L = *(const s16x8*)&bL[(KB) * 512]; \
  S##1H = *(const s16x8*)&bH[8192 + (KB) * 512]; \
  S##1L = *(const s16x8*)&bL[8192 + (KB) * 512];

#define STEP(S, KB) { \
  const int k0_ = ((KB) * 32 + q * 8) ^ ((((KB) >> 1) & 7) << 3); \
  const s16x8 a0_ = *(const s16x8*)&As[m16][k0_]; \
  const s16x8 a1_ = *(const s16x8*)&As[16 + m16][k0_]; \
  MF(a0_, S##0H, acc00); MF(a0_, S##1H, acc01); \
  MF(a1_, S##0H, acc10); MF(a1_, S##1H, acc11); \
  MF(a0_, S##0L, acc00); MF(a0_, S##1L, acc01); \
  MF(a1_, S##0L, acc10); MF(a1_, S##1L, acc11); \
  if ((KB) + 4 < 16) { LD_SET(S, (KB) + 4) } }

template<int FINAL>
__global__ __launch_bounds__(256, 4) void fused_attn(
    const unsigned* __restrict__ mask,
    const float* __restrict__ srcB, const float* __restrict__ dstB,
    const ushort* __restrict__ whtBase,
    float* __restrict__ out, const int ostride,
    const ushort* __restrict__ wcT, const float* __restrict__ bc)
{
  __shared__ ushort As[32][520];
  __shared__ float dstS[544];          // phys = j + (j>>6)*4
  __shared__ float invS[32];
  __shared__ float wredM[4];
  const int t = threadIdx.x;
  const int l = blockIdx.z;
  const float* __restrict__ src = srcB + (long)l * 32768;
  const float* __restrict__ dstv = dstB + (long)l * 32768;
  const ushort* __restrict__ whtH = whtBase + (long)l * WHT_SLOT;
  const ushort* __restrict__ whtL = whtH + 4194304;
  const int ocoff = l * 128;
  // XCD swizzle: per layer 1024 blocks = 8 XCDs x 128; each XCD gets 8 whole
  // batches so a batch's 512KB wht slice is HBM-fetched once, reused via L2.
  const int flat = blockIdx.y * 16 + blockIdx.x;
  const int swz = (flat & 7) * 128 + (flat >> 3);
  const long base = (long)(swz >> 4) * 512;   // batch * 512
  const int i0 = (swz & 15) * 32;             // row tile within batch

  // MFMA geometry + entry prefetch of k-blocks 0..3 + phase-1 global inputs
  // (all independent of the dstS barrier; latency hides under staging).
  const int wv = t >> 6, lane = t & 63;
  const int m16 = lane & 15, q = lane >> 4;
  const int n0 = wv * 32;
  const ushort* __restrict__ bH = whtH + base * 128 + wv * 16384 + lane * 8;
  const ushort* __restrict__ bL = whtL + base * 128 + wv * 16384 + lane * 8;
  s16x8 sA0H, sA0L, sA1H, sA1L, sB0H, sB0L, sB1H, sB1L;
  s16x8 sC0H, sC0L, sC1H, sC1L, sD0H, sD0L, sD1H, sD1L;
  LD_SET(sA, 0)
  LD_SET(sB, 1)
  LD_SET(sC, 2)
  LD_SET(sD, 3)
  const int r1 = t >> 3, l8 = t & 7;
  const long irow = base + i0 + r1;
  const float si = src[irow];
  const uint2 mw2 = *(const uint2*)(mask + irow * 16 + 2 * l8);

  // stage dstS (already log2 domain, padded layout) + block-wide max md
  {
    const float d0 = dstv[base + t];
    const float d1 = dstv[base + t + 256];
    dstS[t + (t >> 6) * 4] = d0;
    const int t2 = t + 256;
    dstS[t2 + (t2 >> 6) * 4] = d1;
    float mx = fmaxf(d0, d1);
#pragma unroll
    for (int w = 1; w < 64; w <<= 1) mx = fmaxf(mx, __shfl_xor(mx, w, 64));
    if ((t & 63) == 0) wredM[t >> 6] = mx;
  }
  __syncthreads();
  const float md = fmaxf(fmaxf(wredM[0], wredM[1]), fmaxf(wredM[2], wredM[3]));

  // ---- phase 1: single-pass masked softmax -> As bf16, invS = 1/rowsum.
  // 8 threads per row, thread l8 owns contiguous j in [l8*64, l8*64+64).
  {
    const float em = si + md;
    const float m = fmaxf(em, ALPHA * em);   // >= masked max of leaky(si+dv)
    const float* __restrict__ dp = &dstS[l8 * 68];
    const int jb = l8 * 64;
    const int xs = l8 << 3;                  // As column XOR swizzle
    float sum = 0.f;
#pragma unroll
    for (int g = 0; g < 16; g++) {
      const float4 dv = *(const float4*)&dp[g * 4];
      const unsigned w = ((g & 8) ? mw2.y : mw2.x) >> ((g & 7) * 4);
      float e0 = si + dv.x, e1 = si + dv.y, e2 = si + dv.z, e3 = si + dv.w;
      e0 = fmaxf(e0, ALPHA * e0) - m; e1 = fmaxf(e1, ALPHA * e1) - m;
      e2 = fmaxf(e2, ALPHA * e2) - m; e3 = fmaxf(e3, ALPHA * e3) - m;
      float p0 = EXP2F(e0), p1 = EXP2F(e1), p2 = EXP2F(e2), p3 = EXP2F(e3);
      p0 = (w & 1u) ? p0 : 0.f;
      p1 = (w & 2u) ? p1 : 0.f;
      p2 = (w & 4u) ? p2 : 0.f;
      p3 = (w & 8u) ? p3 : 0.f;
      sum += (p0 + p1) + (p2 + p3);
      union { __hip_bfloat162 b; unsigned u; } u01, u23;
      u01.b = __float22bfloat162_rn(make_float2(p0, p1));
      u23.b = __float22bfloat162_rn(make_float2(p2, p3));
      *(uint2*)&As[r1][(jb + g * 4) ^ xs] = make_uint2(u01.u, u23.u);
    }
#pragma unroll
    for (int w = 1; w < 8; w <<= 1) sum += __shfl_xor(sum, w, 64);
    if (l8 == 0) invS[r1] = 1.f / sum;
  }
  __syncthreads();

  // ---- phase 2: MFMA aggregation, depth-4 named-register ping-pong.
  // As reads apply the same column XOR: ((kb>>1)&7)<<3, compile-time. ----
  f32x4 acc00 = {0.f,0.f,0.f,0.f}, acc01 = {0.f,0.f,0.f,0.f};
  f32x4 acc10 = {0.f,0.f,0.f,0.f}, acc11 = {0.f,0.f,0.f,0.f};
#pragma unroll
  for (int kp = 0; kp < 4; kp++) {
    STEP(sA, 4 * kp)
    STEP(sB, 4 * kp + 1)
    STEP(sC, 4 * kp + 2)
    STEP(sD, 4 * kp + 3)
  }

  if (!FINAL) {
#pragma unroll
    for (int reg = 0; reg < 4; reg++) {
      const int row = q * 4 + reg;
      const float li0 = invS[row], li1 = invS[16 + row];
      float v00 = acc00[reg] * li0, v01 = acc01[reg] * li0;
      float v10 = acc10[reg] * li1, v11 = acc11[reg] * li1;
      v00 = v00 > 0.f ? v00 : __expf(v00) - 1.f;
      v01 = v01 > 0.f ? v01 : __expf(v01) - 1.f;
      v10 = v10 > 0.f ? v10 : __expf(v10) - 1.f;
      v11 = v11 > 0.f ? v11 : __expf(v11) - 1.f;
      float* o0 = out + (base + i0 + row) * (long)ostride + ocoff + n0 + m16;
      float* o1 = out + (base + i0 + 16 + row) * (long)ostride + ocoff + n0 + m16;
      o0[0] = v00; o0[16] = v01;
      o1[0] = v10; o1[16] = v11;
    }
  } else {
    // ---- fused final GEMM: x (in regs) -> bf16 H/L in As -> x@WcT^T ----
    __syncthreads();   // all phase-2 As reads complete block-wide
#pragma unroll
    for (int reg = 0; reg < 4; reg++) {
      const int row = q * 4 + reg;
      const float li0 = invS[row], li1 = invS[16 + row];
      float v00 = acc00[reg] * li0, v01 = acc01[reg] * li0;
      float v10 = acc10[reg] * li1, v11 = acc11[reg] * li1;
      v00 = v00 > 0.f ? v00 : __expf(v00) - 1.f;
      v01 = v01 > 0.f ? v01 : __expf(v01) - 1.f;
      v10 = v10 > 0.f ? v10 : __expf(v10) - 1.f;
      v11 = v11 > 0.f ? v11 : __expf(v11) - 1.f;
      ushort h;
      h = bf16_rne(v00); As[row][n0 + m16] = h;
      As[row][264 + n0 + m16] = bf16_rne(v00 - bf16_tof(h));
      h = bf16_rne(v01); As[row][n0 + 16 + m16] = h;
      As[row][264 + n0 + 16 + m16] = bf16_rne(v01 - bf16_tof(h));
      h = bf16_rne(v10); As[16 + row][n0 + m16] = h;
      As[16 + row][264 + n0 + m16] = bf16_rne(v10 - bf16_tof(h));
      h = bf16_rne(v11); As[16 + row][n0 + 16 + m16] = h;
      As[16 + row][264 + n0 + 16 + m16] = bf16_rne(v11 - bf16_tof(h));
    }
    __syncthreads();
    // second GEMM: [32x256] = x[32x128] @ WcT^T; wave wv owns cols
    // [wv*64, wv*64+64). Same per-acc add order as the old final gemm.
    f32x4 a2[2][4];
#pragma unroll
    for (int m2 = 0; m2 < 2; m2++)
#pragma unroll
      for (int n = 0; n < 4; n++) a2[m2][n] = (f32x4){0.f, 0.f, 0.f, 0.f};
#pragma unroll
    for (int kb = 0; kb < 4; kb++) {
      const int k0 = kb * 32 + q * 8;
      const s16x8 aH0 = *(const s16x8*)&As[m16][k0];
      const s16x8 aL0 = *(const s16x8*)&As[m16][264 + k0];
      const s16x8 aH1 = *(const s16x8*)&As[16 + m16][k0];
      const s16x8 aL1 = *(const s16x8*)&As[16 + m16][264 + k0];
#pragma unroll
      for (int n = 0; n < 4; n++) {
        const ushort* wp = wcT + (wv * 4 + n) * 2048 + kb * 512 + lane * 8;
        const s16x8 bh = *(const s16x8*)wp;
        const s16x8 bl = *(const s16x8*)(wp + 32768);
        MF(aH0, bh, a2[0][n]); MF(aL0, bh, a2[0][n]); MF(aH0, bl, a2[0][n]);
        MF(aH1, bh, a2[1][n]); MF(aL1, bh, a2[1][n]); MF(aH1, bl, a2[1][n]);
      }
    }
#pragma unroll
    for (int m2 = 0; m2 < 2; m2++)
#pragma unroll
      for (int n = 0; n < 4; n++) {
        const int c = wv * 64 + n * 16 + m16;
        const float bv = bc[c];
#pragma unroll
        for (int reg = 0; reg < 4; reg++) {
          float v = a2[m2][n][reg] + bv;
          v = fmaxf(v, ALPHA * v);
          out[(base + i0 + m2 * 16 + q * 4 + reg) * 256L + c] = v;
        }
      }
  }
}

// ---- K3: MFMA GEMM, C = A[32768,384] @ BT^T, 32 rows x 128 cols/block.
// A fp32 -> bf16 hi/lo during LDS staging; B fragment-order (coalesced 1KB
// loads). MODE 0: emit whT (fragment order) + src/dst; blocks [1024,1152)
// do the Wc split (bias=Wc, outF=WcT_H); blocks [1152,1280) copy the mask
// from d_out to the slot-1 parking (race-free for the FINAL kernel).
// MODE 1 retained for reference (unused). ----
template<int K, int KC, int MODE>
__global__ __launch_bounds__(256) void mfma_gemm(
    const float* __restrict__ A,
    const ushort* __restrict__ BTH, const ushort* __restrict__ BTL,
    const float* __restrict__ bias, float* __restrict__ outF,
    ushort* __restrict__ whtH, ushort* __restrict__ whtL,
    const float* __restrict__ avec, float* __restrict__ src, float* __restrict__ dst,
    const int ostride,
    const unsigned* __restrict__ maskSrc, unsigned* __restrict__ maskDst)
{
  constexpr int KP = KC + 8;
  __shared__ ushort AsH[32][KP];
  __shared__ ushort AsL[32][KP];
  __shared__ float sredS[4][32], sredD[4][32];
  const int t = threadIdx.x;

  if (MODE == 0 && blockIdx.x >= 1024) {
    const int xb = (int)blockIdx.x - 1024;
    if (xb < 128) {
      // ---- folded wt_prep(Wc): [128,256] fp32 -> fragment-order WcT.
      // bias == Wc, outF == WcT_H (WcT_L contiguous at +32768).
      const int idx = xb * 256 + t;                     // 32768 exact
      const int k = idx >> 8, n = idx & 255;
      const float v = bias[idx];
      const ushort h = bf16_rne(v);
      const long o = w_frag_off(n, k, 128);
      ushort* __restrict__ WcTH = (ushort*)outF;
      WcTH[o] = h;
      WcTH[32768 + o] = bf16_rne(v - bf16_tof(h));
    } else {
      // ---- mask copy d_out -> slot-1 (131072 uint4 total) ----
      const int gid = (xb - 128) * 256 + t;             // [0,32768)
      const uint4* __restrict__ s4 = (const uint4*)maskSrc;
      uint4* __restrict__ d4 = (uint4*)maskDst;
      d4[gid] = s4[gid];
      d4[gid + 32768] = s4[gid + 32768];
      d4[gid + 65536] = s4[gid + 65536];
      d4[gid + 98304] = s4[gid + 98304];
    }
    return;
  }

  const long row0 = (long)blockIdx.x * 32;
  const int ncoff = (MODE == 1) ? blockIdx.y * 128 : 0;

  const int wv = t >> 6, lane = t & 63;
  const int m16 = lane & 15, q = lane >> 4;
  const int n0 = wv * 32;
  // fragment-order B: tile (ncoff+n0)/16, lane*8; next 16-col tile at +K*16
  const ushort* __restrict__ bh0 = BTH + (long)((ncoff + n0) >> 4) * (K * 16) + lane * 8;
  const ushort* __restrict__ bl0 = BTL + (long)((ncoff + n0) >> 4) * (K * 16) + lane * 8;

  f32x4 acc[2][2];
#pragma unroll
  for (int m = 0; m < 2; m++)
#pragma unroll
    for (int n = 0; n < 2; n++) acc[m][n] = (f32x4){0.f, 0.f, 0.f, 0.f};

  for (int kc = 0; kc < K; kc += KC) {
    constexpr int NIT = (32 * KC / 4) / 256;
#pragma unroll
    for (int it = 0; it < NIT; it++) {
      const int idx = t + it * 256;
      const int r = idx / (KC / 4), k4 = idx % (KC / 4);
      const float4 v = *(const float4*)&A[(row0 + r) * (long)K + kc + k4 * 4];
      split_store4(&AsH[r][k4 * 4], &AsL[r][k4 * 4], v.x, v.y, v.z, v.w);
    }
    __syncthreads();
#pragma unroll
    for (int ks = 0; ks < KC / 32; ks++) {
      const int k0 = ks * 32 + q * 8;
      const s16x8 a0H = *(const s16x8*)&AsH[m16][k0];
      const s16x8 a0L = *(const s16x8*)&AsL[m16][k0];
      const s16x8 a1H = *(const s16x8*)&AsH[16 + m16][k0];
      const s16x8 a1L = *(const s16x8*)&AsL[16 + m16][k0];
      const int bo = ((kc >> 5) + ks) * 512;
      const s16x8 b0H = *(const s16x8*)&bh0[bo];
      const s16x8 b0L = *(const s16x8*)&bl0[bo];
      const s16x8 b1H = *(const s16x8*)&bh0[K * 16 + bo];
      const s16x8 b1L = *(const s16x8*)&bl0[K * 16 + bo];
      acc[0][0] = __builtin_amdgcn_mfma_f32_16x16x32_bf16(a0H, b0H, acc[0][0], 0, 0, 0);
      acc[0][1] = __builtin_amdgcn_mfma_f32_16x16x32_bf16(a0H, b1H, acc[0][1], 0, 0, 0);
      acc[1][0] = __builtin_amdgcn_mfma_f32_16x16x32_bf16(a1H, b0H, acc[1][0], 0, 0, 0);
      acc[1][1] = __builtin_amdgcn_mfma_f32_16x16x32_bf16(a1H, b1H, acc[1][1], 0, 0, 0);
      acc[0][0] = __builtin_amdgcn_mfma_f32_16x16x32_bf16(a0L, b0H, acc[0][0], 0, 0, 0);
      acc[0][1] = __builtin_amdgcn_mfma_f32_16x16x32_bf16(a0L, b1H, acc[0][1], 0, 0, 0);
      acc[1][0] = __builtin_amdgcn_mfma_f32_16x16x32_bf16(a1L, b0H, acc[1][0], 0, 0, 0);
      acc[1][1] = __builtin_amdgcn_mfma_f32_16x16x32_bf16(a1L, b1H, acc[1][1], 0, 0, 0);
      acc[0][0] = __builtin_amdgcn_mfma_f32_16x16x32_bf16(a0H, b0L, acc[0][0], 0, 0, 0);
      acc[0][1] = __builtin_amdgcn_mfma_f32_16x16x32_bf16(a0H, b1L, acc[0][1], 0, 0, 0);
      acc[1][0] = __builtin_amdgcn_mfma_f32_16x16x32_bf16(a1H, b0L, acc[1][0], 0, 0, 0);
      acc[1][1] = __builtin_amdgcn_mfma_f32_16x16x32_bf16(a1H, b1L, acc[1][1], 0, 0, 0);
    }
    __syncthreads();
  }

  if (MODE == 0) {
    // whT hi/lo store in fragment order
    const long batch = row0 >> 9;
    const int iloc = (int)(row0 & 511);
#pragma unroll
    for (int m = 0; m < 2; m++)
#pragma unroll
      for (int n = 0; n < 2; n++) {
        const int c = n0 + n * 16 + m16;
        const int j = iloc + m * 16 + q * 4;        // j%4 == 0 -> contiguous 4
        const long o = wht_off(batch, c, j);
        const f32x4 v = acc[m][n];
        split_store4(&whtH[o], &whtL[o], v[0], v[1], v[2], v[3]);
      }
    // fused src/dst: reduce over cols (16 lanes x 2 n-tiles per wave, 4 waves)
    const float a10 = avec[n0 + m16], a11 = avec[n0 + 16 + m16];
    const float a20 = avec[128 + n0 + m16], a21 = avec[128 + n0 + 16 + m16];
#pragma unroll
    for (int m = 0; m < 2; m++) {
#pragma unroll
      for (int reg = 0; reg < 4; reg++) {
        float s = acc[m][0][reg] * a10 + acc[m][1][reg] * a11;
        float d = acc[m][0][reg] * a20 + acc[m][1][reg] * a21;
#pragma unroll
        for (int w = 1; w < 16; w <<= 1) {
          s += __shfl_xor(s, w, 64);
          d += __shfl_xor(d, w, 64);
        }
        if (m16 == 0) {
          const int row = m * 16 + q * 4 + reg;
          sredS[wv][row] = s;
          sredD[wv][row] = d;
        }
      }
    }
    __syncthreads();
    if (t < 32) {
      const float s = sredS[0][t] + sredS[1][t] + sredS[2][t] + sredS[3][t];
      const float d = sredD[0][t] + sredD[1][t] + sredD[2][t] + sredD[3][t];
      src[row0 + t] = s * LOG2E;   // log2-domain at producer
      dst[row0 + t] = d * LOG2E;
    }
  } else {
#pragma unroll
    for (int m = 0; m < 2; m++)
#pragma unroll
      for (int n = 0; n < 2; n++) {
        const int c = ncoff + n0 + n * 16 + m16;
        const float bv = bias[c];
#pragma unroll
        for (int reg = 0; reg < 4; reg++) {
          float v = acc[m][n][reg] + bv;
          v = fmaxf(v, ALPHA * v);
          outF[(row0 + m * 16 + q * 4 + reg) * (long)ostride + c] = v;
        }
      }
  }
}

extern "C" void kernel_launch(void* const* d_in, const int* in_sizes, int n_in,
                              void* d_out, int out_size, void* d_ws, size_t ws_size,
                              hipStream_t stream) {
  const float* compound = (const float*)d_in[0];
  const int*   adj      = (const int*)d_in[1];
  const float* W_stack  = (const float*)d_in[2];
  const float* a_stack  = (const float*)d_in[3];
  const float* W_out    = (const float*)d_in[4];
  const float* a_out    = (const float*)d_in[5];
  const float* Wc       = (const float*)d_in[6];
  const float* bc       = (const float*)d_in[7];
  float* out = (float*)d_out;

  // workspace: wht slots for 3 layers (48MB), then multi (50MB).
  // Slot-1 is dead after the merged fused_attn; it then hosts (written by
  // gemm384's extra blocks, read by the FINAL kernel):
  //   WcT 65536 ushorts | mask copy 524288 uints | src3/dst3 65536 floats
  ushort* wht_all = (ushort*)d_ws;                    // 3 x 16MB slots
  float* f     = (float*)d_ws;
  float* multi = f + 12582912;                        // 12,582,912 floats
  ushort* WcT_H = wht_all + WHT_SLOT;                 // slot-1 head
  unsigned* maskS1 = (unsigned*)(wht_all + WHT_SLOT + 65536);
  float* src3b = (float*)(wht_all + WHT_SLOT + 65536 + 1048576);
  float* dst3b = src3b + 32768;

  // d_out parking (dead after gemm384; FINAL kernel then overwrites d_out):
  // mask 524288 uints | src[3]/dst[3] (layer src/dst) | WoT_H/L
  unsigned* mask = (unsigned*)d_out;
  float* doutF = (float*)d_out;
  float* srcB = doutF + 524288;                       // 3 x 32768 used
  float* dstB = srcB + 4 * 32768;
  ushort* WoT_H = (ushort*)(dstB + 4 * 32768);        // 98304 ushorts
  ushort* WoT_L = WoT_H + 98304;

  // front: wh_small x3 + maskprep + wt_prep(W_out), INTERLEAVED, one dispatch
  front_union<<<5312, 256, 0, stream>>>(
      compound, W_stack, a_stack, wht_all, srcB, dstB,
      adj, mask, W_out, WoT_H, WoT_L);
  // 3 GAT heads
  fused_attn<0><<<dim3(16, 64, 3), 256, 0, stream>>>(
      mask, srcB, dstB, wht_all, multi, 384, nullptr, nullptr);
  // layer 4: Wh = multi @ W_out (MFMA, emits whT slot-0 + src/dst -> slot-1);
  // blocks [1024,1152) Wc split -> slot-1; [1152,1280) mask copy -> slot-1
  mfma_gemm<384, 192, 0><<<1280, 256, 0, stream>>>(
      multi, WoT_H, WoT_L, Wc, (float*)WcT_H, wht_all, wht_all + 4194304,
      a_out, src3b, dst3b, 0, mask, maskS1);
  // layer-4 attention + fused final GEMM -> d_out (reads only workspace)
  fused_attn<1><<<dim3(16, 64, 1), 256, 0, stream>>>(
      maskS1, src3b, dst3b, wht_all, out, 256, WcT_H, bc);
}